// Round 1
// baseline (849.169 us; speedup 1.0000x reference)
//
#include <hip/hip_runtime.h>
#include <hip/hip_bf16.h>
#include <cstdint>
#include <cstddef>

// ---------- types ----------
typedef __bf16 bf16x8 __attribute__((ext_vector_type(8)));
typedef float  f32x4  __attribute__((ext_vector_type(4)));

__device__ __forceinline__ unsigned short f2bf(float f) {
  union { float f; unsigned u; } v; v.f = f;
  unsigned u = v.u;
  u += 0x7FFFu + ((u >> 16) & 1u);   // RNE
  return (unsigned short)(u >> 16);
}

struct alignas(16) US8 { unsigned short u[8]; };

// sizes
#define BB 2
#define SS 1024
#define HID 1024
#define NHH 16
#define HDD 64
#define TT 4096
#define CCH 3072

// ---------- LayerNorm (complex) -> Aln bf16 [2048][2048] = [nr | ni] ----------
__global__ __launch_bounds__(256) void ln_kernel(
    const float* __restrict__ hre, const float* __restrict__ him,
    const float* __restrict__ gamma, const float* __restrict__ bre,
    const float* __restrict__ bim, unsigned short* __restrict__ Aln)
{
  int m = blockIdx.x;
  int tid = threadIdx.x;
  const float4 vr = ((const float4*)(hre + (size_t)m * HID))[tid];
  const float4 vi = ((const float4*)(him + (size_t)m * HID))[tid];
  float sr = vr.x + vr.y + vr.z + vr.w;
  float si = vi.x + vi.y + vi.z + vi.w;
  float sq = vr.x*vr.x + vr.y*vr.y + vr.z*vr.z + vr.w*vr.w
           + vi.x*vi.x + vi.y*vi.y + vi.z*vi.z + vi.w*vi.w;
  __shared__ float red[3][4];
  int lane = tid & 63, w = tid >> 6;
  for (int off = 32; off; off >>= 1) {
    sr += __shfl_down(sr, off, 64);
    si += __shfl_down(si, off, 64);
    sq += __shfl_down(sq, off, 64);
  }
  if (lane == 0) { red[0][w] = sr; red[1][w] = si; red[2][w] = sq; }
  __syncthreads();
  sr = red[0][0] + red[0][1] + red[0][2] + red[0][3];
  si = red[1][0] + red[1][1] + red[1][2] + red[1][3];
  sq = red[2][0] + red[2][1] + red[2][2] + red[2][3];
  float mur = sr * (1.f/1024.f), mui = si * (1.f/1024.f);
  float var = sq * (1.f/1024.f) - mur*mur - mui*mui;
  float inv = rsqrtf(var + 1e-5f);
  int k = tid * 4;
  float4 g  = ((const float4*)gamma)[tid];
  float4 br = ((const float4*)bre)[tid];
  float4 bi = ((const float4*)bim)[tid];
  ushort4 nr, ni;
  nr.x = f2bf((vr.x - mur) * inv * g.x + br.x);
  nr.y = f2bf((vr.y - mur) * inv * g.y + br.y);
  nr.z = f2bf((vr.z - mur) * inv * g.z + br.z);
  nr.w = f2bf((vr.w - mur) * inv * g.w + br.w);
  ni.x = f2bf((vi.x - mui) * inv * g.x + bi.x);
  ni.y = f2bf((vi.y - mui) * inv * g.y + bi.y);
  ni.z = f2bf((vi.z - mui) * inv * g.z + bi.z);
  ni.w = f2bf((vi.w - mui) * inv * g.w + bi.w);
  *(ushort4*)&Aln[(size_t)m * 2048 + k]        = nr;
  *(ushort4*)&Aln[(size_t)m * 2048 + 1024 + k] = ni;
}

// ---------- combined weights: Wc[p][n][k] bf16, p in {q,k,v,o}, 2048x2048 each ----------
// n<1024: [Wr | -Wi], n>=1024: [Wi | Wr]
__global__ __launch_bounds__(256) void wprep_kernel(
    const float* __restrict__ qWr, const float* __restrict__ qWi,
    const float* __restrict__ kWr, const float* __restrict__ kWi,
    const float* __restrict__ vWr, const float* __restrict__ vWi,
    const float* __restrict__ oWr, const float* __restrict__ oWi,
    unsigned short* __restrict__ Wc)
{
  int gid = blockIdx.x * 256 + threadIdx.x;
  int idx = gid * 8;                     // over 4*2048*2048
  int p   = idx >> 22;
  int rem = idx & 0x3FFFFF;
  int n   = rem >> 11;
  int k   = rem & 2047;
  const float* Wr; const float* Wi;
  switch (p) {
    case 0:  Wr = qWr; Wi = qWi; break;
    case 1:  Wr = kWr; Wi = kWi; break;
    case 2:  Wr = vWr; Wi = vWi; break;
    default: Wr = oWr; Wi = oWi; break;
  }
  const float* src; float sgn = 1.f;
  if (n < 1024) {
    if (k < 1024) src = Wr + (size_t)n * 1024 + k;
    else        { src = Wi + (size_t)n * 1024 + (k - 1024); sgn = -1.f; }
  } else {
    if (k < 1024) src = Wi + (size_t)(n - 1024) * 1024 + k;
    else          src = Wr + (size_t)(n - 1024) * 1024 + (k - 1024);
  }
  float4 a = ((const float4*)src)[0];
  float4 b = ((const float4*)src)[1];
  US8 o;
  o.u[0] = f2bf(a.x * sgn); o.u[1] = f2bf(a.y * sgn);
  o.u[2] = f2bf(a.z * sgn); o.u[3] = f2bf(a.w * sgn);
  o.u[4] = f2bf(b.x * sgn); o.u[5] = f2bf(b.y * sgn);
  o.u[6] = f2bf(b.z * sgn); o.u[7] = f2bf(b.w * sgn);
  *(US8*)&Wc[idx] = o;
}

__global__ __launch_bounds__(256) void bprep_kernel(
    const float* __restrict__ qbr, const float* __restrict__ qbi,
    const float* __restrict__ kbr, const float* __restrict__ kbi,
    const float* __restrict__ vbr, const float* __restrict__ vbi,
    const float* __restrict__ obr, const float* __restrict__ obi,
    float* __restrict__ bc)
{
  int idx = blockIdx.x * 256 + threadIdx.x;  // 8192
  int p = idx >> 11, n = idx & 2047;
  const float* br; const float* bi;
  switch (p) {
    case 0:  br = qbr; bi = qbi; break;
    case 1:  br = kbr; bi = kbi; break;
    case 2:  br = vbr; bi = vbi; break;
    default: br = obr; bi = obi; break;
  }
  bc[idx] = (n < 1024) ? br[n] : bi[n - 1024];
}

// ---------- GEMM: C[M x N] = A[M x K] * B[N x K]^T + bias[n], bf16 in, f32 out ----------
// 128x128 tile, 4 waves, each wave 64x64 quadrant of 4x4 16x16 MFMAs, BK=32.
__global__ __launch_bounds__(256) void gemm_bt_kernel(
    const unsigned short* __restrict__ A, const unsigned short* __restrict__ Bm,
    const float* __restrict__ bias, float* __restrict__ C, int Nstride, int K)
{
  __shared__ alignas(16) unsigned short As[128][32];
  __shared__ alignas(16) unsigned short Bs[128][32];
  int bm = blockIdx.y * 128;
  int bn = blockIdx.x * 128;
  int tid = threadIdx.x;
  int lane = tid & 63, w = tid >> 6;
  int wm = (w >> 1) * 64, wn = (w & 1) * 64;
  int l15 = lane & 15, q = lane >> 4;
  int lr = tid >> 2;            // 0..63
  int lc = (tid & 3) * 8;       // 0,8,16,24

  f32x4 acc[4][4] = {};

  for (int k0 = 0; k0 < K; k0 += 32) {
    *(float4*)&As[lr][lc]    = *(const float4*)&A [(size_t)(bm + lr)      * K + k0 + lc];
    *(float4*)&As[lr+64][lc] = *(const float4*)&A [(size_t)(bm + lr + 64) * K + k0 + lc];
    *(float4*)&Bs[lr][lc]    = *(const float4*)&Bm[(size_t)(bn + lr)      * K + k0 + lc];
    *(float4*)&Bs[lr+64][lc] = *(const float4*)&Bm[(size_t)(bn + lr + 64) * K + k0 + lc];
    __syncthreads();
    bf16x8 af[4], bfr[4];
#pragma unroll
    for (int i = 0; i < 4; i++) af[i]  = *(const bf16x8*)&As[wm + i*16 + l15][q*8];
#pragma unroll
    for (int i = 0; i < 4; i++) bfr[i] = *(const bf16x8*)&Bs[wn + i*16 + l15][q*8];
#pragma unroll
    for (int i = 0; i < 4; i++)
#pragma unroll
      for (int j = 0; j < 4; j++)
        acc[i][j] = __builtin_amdgcn_mfma_f32_16x16x32_bf16(af[i], bfr[j], acc[i][j], 0, 0, 0);
    __syncthreads();
  }

#pragma unroll
  for (int i = 0; i < 4; i++)
#pragma unroll
    for (int j = 0; j < 4; j++) {
      int n = bn + wn + j*16 + l15;
      float bv = bias[n];
#pragma unroll
      for (int r = 0; r < 4; r++) {
        int m = bm + wm + i*16 + q*4 + r;
        C[(size_t)m * Nstride + n] = acc[i][j][r] + bv;
      }
    }
}

// ---------- o-proj GEMM with residual + split write to out_re/out_im ----------
__global__ __launch_bounds__(256) void gemm_oproj_kernel(
    const unsigned short* __restrict__ A, const unsigned short* __restrict__ Bm,
    const float* __restrict__ bias, const float* __restrict__ hre,
    const float* __restrict__ him, float* __restrict__ out)
{
  __shared__ alignas(16) unsigned short As[128][32];
  __shared__ alignas(16) unsigned short Bs[128][32];
  int bm = blockIdx.y * 128;
  int bn = blockIdx.x * 128;
  int tid = threadIdx.x;
  int lane = tid & 63, w = tid >> 6;
  int wm = (w >> 1) * 64, wn = (w & 1) * 64;
  int l15 = lane & 15, q = lane >> 4;
  int lr = tid >> 2;
  int lc = (tid & 3) * 8;
  const int K = 2048;

  f32x4 acc[4][4] = {};

  for (int k0 = 0; k0 < K; k0 += 32) {
    *(float4*)&As[lr][lc]    = *(const float4*)&A [(size_t)(bm + lr)      * K + k0 + lc];
    *(float4*)&As[lr+64][lc] = *(const float4*)&A [(size_t)(bm + lr + 64) * K + k0 + lc];
    *(float4*)&Bs[lr][lc]    = *(const float4*)&Bm[(size_t)(bn + lr)      * K + k0 + lc];
    *(float4*)&Bs[lr+64][lc] = *(const float4*)&Bm[(size_t)(bn + lr + 64) * K + k0 + lc];
    __syncthreads();
    bf16x8 af[4], bfr[4];
#pragma unroll
    for (int i = 0; i < 4; i++) af[i]  = *(const bf16x8*)&As[wm + i*16 + l15][q*8];
#pragma unroll
    for (int i = 0; i < 4; i++) bfr[i] = *(const bf16x8*)&Bs[wn + i*16 + l15][q*8];
#pragma unroll
    for (int i = 0; i < 4; i++)
#pragma unroll
      for (int j = 0; j < 4; j++)
        acc[i][j] = __builtin_amdgcn_mfma_f32_16x16x32_bf16(af[i], bfr[j], acc[i][j], 0, 0, 0);
    __syncthreads();
  }

#pragma unroll
  for (int i = 0; i < 4; i++)
#pragma unroll
    for (int j = 0; j < 4; j++) {
      int n = bn + wn + j*16 + l15;
      float bv = bias[n];
#pragma unroll
      for (int r = 0; r < 4; r++) {
        int m = bm + wm + i*16 + q*4 + r;
        float val = acc[i][j][r] + bv;
        if (n < 1024) out[(size_t)m * 1024 + n] = val + hre[(size_t)m * 1024 + n];
        else out[2097152 + (size_t)m * 1024 + (n - 1024)] = val + him[(size_t)m * 1024 + (n - 1024)];
      }
    }
}

// ---------- pack Q: Cqkv cols [0,2048) -> Qp[bh][s][128] bf16, scaled by 1/8 ----------
__global__ __launch_bounds__(256) void pack_q_kernel(
    const float* __restrict__ Cqkv, unsigned short* __restrict__ Qp)
{
  int gid = blockIdx.x * 256 + threadIdx.x;
  int idx = gid * 4;                 // over 2*16*1024*128 = 4,194,304
  int d2 = idx & 127;
  int s  = (idx >> 7) & 1023;
  int bh = idx >> 17;
  int b = bh >> 4, h = bh & 15;
  int d = d2 & 63;
  int col = (d2 < 64) ? (h*64 + d) : (1024 + h*64 + d);
  float4 v = *(const float4*)&Cqkv[((size_t)b * 1024 + s) * 6144 + col];
  ushort4 o;
  o.x = f2bf(v.x * 0.125f); o.y = f2bf(v.y * 0.125f);
  o.z = f2bf(v.z * 0.125f); o.w = f2bf(v.w * 0.125f);
  *(ushort4*)&Qp[idx] = o;
}

// ---------- pack K or V: cache + Cqkv -> packed bf16 [bh][t][128] (optional) + new_* f32 outputs ----------
__global__ __launch_bounds__(256) void pack_kv_kernel(
    const float* __restrict__ c_re, const float* __restrict__ c_im,
    const float* __restrict__ Cqkv, int colbase,
    unsigned short* __restrict__ Kp,
    float* __restrict__ out_re, float* __restrict__ out_im)
{
  int gid = blockIdx.x * 256 + threadIdx.x;
  int idx = gid * 4;                 // over 2*16*4096*128 = 16,777,216
  int d2 = idx & 127;
  int t  = (idx >> 7) & 4095;
  int bh = idx >> 19;
  int b = bh >> 4, h = bh & 15;
  int d = d2 & 63;
  bool im = d2 >= 64;
  float4 v;
  if (t < CCH) {
    const float* src = im ? c_im : c_re;
    v = *(const float4*)&src[(((size_t)b * CCH + t) * 16 + h) * 64 + d];
  } else {
    int col = colbase + (im ? (1024 + h*64 + d) : (h*64 + d));
    v = *(const float4*)&Cqkv[((size_t)b * 1024 + (t - CCH)) * 6144 + col];
  }
  if (Kp) {
    ushort4 o;
    o.x = f2bf(v.x); o.y = f2bf(v.y); o.z = f2bf(v.z); o.w = f2bf(v.w);
    *(ushort4*)&Kp[idx] = o;
  }
  float* dst = im ? out_im : out_re;
  *(float4*)&dst[(((size_t)b * 4096 + t) * 16 + h) * 64 + d] = v;
}

// ---------- pack V transposed: Vt[bh][d2][t] bf16 ----------
__global__ __launch_bounds__(256) void pack_vt_kernel(
    const float* __restrict__ Vc_re, const float* __restrict__ Vc_im,
    const float* __restrict__ Cqkv, unsigned short* __restrict__ Vt)
{
  int gid = blockIdx.x * 256 + threadIdx.x;
  int idx = gid * 4;                 // over 2*16*128*4096 = 16,777,216
  int t4 = idx & 4095;
  int d2 = (idx >> 12) & 127;
  int bh = idx >> 19;
  int b = bh >> 4, h = bh & 15;
  int d = d2 & 63;
  const float* Vc = (d2 < 64) ? Vc_re : Vc_im;
  int colq = 4096 + ((d2 < 64) ? (h*64 + d) : (1024 + h*64 + d));
  ushort4 o;
  unsigned short ov[4];
#pragma unroll
  for (int j = 0; j < 4; j++) {
    int t = t4 + j;
    float val;
    if (t < CCH) val = Vc[(((size_t)b * CCH + t) * 16 + h) * 64 + d];
    else         val = Cqkv[((size_t)b * 1024 + (t - CCH)) * 6144 + colq];
    ov[j] = f2bf(val);
  }
  o.x = ov[0]; o.y = ov[1]; o.z = ov[2]; o.w = ov[3];
  *(ushort4*)&Vt[idx] = o;
}

// ---------- flash attention: per (b,h), 64 q-rows per wg, online softmax ----------
// Qp [bh][s][128] (pre-scaled), Kp [bh][t][128], Vt [bh][d2][t]; out Ao bf16 [m][n] layout
__global__ __launch_bounds__(256) void attn_kernel(
    const unsigned short* __restrict__ Qp, const unsigned short* __restrict__ Kp,
    const unsigned short* __restrict__ Vt, unsigned short* __restrict__ Ao)
{
  int s0 = blockIdx.x * 64;
  int bh = blockIdx.y;
  int b = bh >> 4, h = bh & 15;
  int tid = threadIdx.x;
  int lane = tid & 63, w = tid >> 6;
  int l15 = lane & 15, q = lane >> 4;

  __shared__ alignas(16) unsigned short Ks[32][128];
  __shared__ alignas(16) unsigned short Vs[128][32];
  __shared__ alignas(16) unsigned short Ps[4][16][32];

  bf16x8 qf[4];
  {
    const size_t qbase = ((size_t)bh * 1024 + s0 + w*16 + l15) * 128;
#pragma unroll
    for (int kc = 0; kc < 4; kc++)
      qf[kc] = *(const bf16x8*)&Qp[qbase + kc*32 + q*8];
  }

  f32x4 oacc[8] = {};
  float mrow[4] = {-3e38f, -3e38f, -3e38f, -3e38f};
  float lrow[4] = {0.f, 0.f, 0.f, 0.f};

  const size_t kpb = (size_t)bh * 4096 * 128;
  const size_t vtb = (size_t)bh * 128 * 4096;
  const int tmax = s0 + 64 + CCH;     // exclusive bound over t tiles

  int kr = tid >> 3, kcl = (tid & 7) * 16;
  int vr = tid >> 1, vcl = (tid & 1) * 16;

  for (int t0 = 0; t0 < tmax; t0 += 32) {
    *(float4*)&Ks[kr][kcl]     = *(const float4*)&Kp[kpb + (size_t)(t0 + kr) * 128 + kcl];
    *(float4*)&Ks[kr][kcl + 8] = *(const float4*)&Kp[kpb + (size_t)(t0 + kr) * 128 + kcl + 8];
    *(float4*)&Vs[vr][vcl]     = *(const float4*)&Vt[vtb + (size_t)vr * 4096 + t0 + vcl];
    *(float4*)&Vs[vr][vcl + 8] = *(const float4*)&Vt[vtb + (size_t)vr * 4096 + t0 + vcl + 8];
    __syncthreads();

    f32x4 sacc[2] = {};
#pragma unroll
    for (int nc = 0; nc < 2; nc++)
#pragma unroll
      for (int kc = 0; kc < 4; kc++) {
        bf16x8 kf = *(const bf16x8*)&Ks[nc*16 + l15][kc*32 + q*8];
        sacc[nc] = __builtin_amdgcn_mfma_f32_16x16x32_bf16(qf[kc], kf, sacc[nc], 0, 0, 0);
      }

    float pv[2][4];
#pragma unroll
    for (int r = 0; r < 4; r++) {
      int sg = s0 + w*16 + q*4 + r;
      int tlim = sg + CCH;
      float v0 = sacc[0][r]; if (t0 + l15 > tlim)      v0 = -1e30f;
      float v1 = sacc[1][r]; if (t0 + 16 + l15 > tlim) v1 = -1e30f;
      float mt = fmaxf(v0, v1);
      mt = fmaxf(mt, __shfl_xor(mt, 1, 64));
      mt = fmaxf(mt, __shfl_xor(mt, 2, 64));
      mt = fmaxf(mt, __shfl_xor(mt, 4, 64));
      mt = fmaxf(mt, __shfl_xor(mt, 8, 64));
      float mn = fmaxf(mrow[r], mt);
      float alpha = __expf(mrow[r] - mn);
      float p0 = __expf(v0 - mn);
      float p1 = __expf(v1 - mn);
      float ps = p0 + p1;
      ps += __shfl_xor(ps, 1, 64);
      ps += __shfl_xor(ps, 2, 64);
      ps += __shfl_xor(ps, 4, 64);
      ps += __shfl_xor(ps, 8, 64);
      lrow[r] = lrow[r] * alpha + ps;
      mrow[r] = mn;
#pragma unroll
      for (int dc = 0; dc < 8; dc++) oacc[dc][r] *= alpha;
      pv[0][r] = p0; pv[1][r] = p1;
    }
#pragma unroll
    for (int r = 0; r < 4; r++) {
      Ps[w][q*4 + r][l15]      = f2bf(pv[0][r]);
      Ps[w][q*4 + r][16 + l15] = f2bf(pv[1][r]);
    }
    bf16x8 pf = *(const bf16x8*)&Ps[w][l15][q*8];
#pragma unroll
    for (int dc = 0; dc < 8; dc++) {
      bf16x8 vf = *(const bf16x8*)&Vs[dc*16 + l15][q*8];
      oacc[dc] = __builtin_amdgcn_mfma_f32_16x16x32_bf16(pf, vf, oacc[dc], 0, 0, 0);
    }
    __syncthreads();
  }

#pragma unroll
  for (int dc = 0; dc < 8; dc++)
#pragma unroll
    for (int r = 0; r < 4; r++) {
      int s = s0 + w*16 + q*4 + r;
      int d2 = dc*16 + l15;
      float val = oacc[dc][r] / lrow[r];
      int m = b * 1024 + s;
      int n = (d2 < 64) ? (h*64 + d2) : (1024 + h*64 + (d2 - 64));
      Ao[(size_t)m * 2048 + n] = f2bf(val);
    }
}

// ---------- launch ----------
extern "C" void kernel_launch(void* const* d_in, const int* in_sizes, int n_in,
                              void* d_out, int out_size, void* d_ws, size_t ws_size,
                              hipStream_t stream)
{
  (void)in_sizes; (void)n_in; (void)out_size; (void)ws_size;
  const float* hre = (const float*)d_in[0];
  const float* him = (const float*)d_in[1];
  const float* Kcr = (const float*)d_in[2];
  const float* Kci = (const float*)d_in[3];
  const float* Vcr = (const float*)d_in[4];
  const float* Vci = (const float*)d_in[5];
  const float* gamma = (const float*)d_in[6];
  const float* bre = (const float*)d_in[7];
  const float* bim = (const float*)d_in[8];
  const float* qWr = (const float*)d_in[9];
  const float* qWi = (const float*)d_in[10];
  const float* qbr = (const float*)d_in[11];
  const float* qbi = (const float*)d_in[12];
  const float* kWr = (const float*)d_in[13];
  const float* kWi = (const float*)d_in[14];
  const float* kbr = (const float*)d_in[15];
  const float* kbi = (const float*)d_in[16];
  const float* vWr = (const float*)d_in[17];
  const float* vWi = (const float*)d_in[18];
  const float* vbr = (const float*)d_in[19];
  const float* vbi = (const float*)d_in[20];
  const float* oWr = (const float*)d_in[21];
  const float* oWi = (const float*)d_in[22];
  const float* obr = (const float*)d_in[23];
  const float* obi = (const float*)d_in[24];
  float* out = (float*)d_out;

  char* ws = (char*)d_ws;
  size_t off = 0;
  auto carve = [&](size_t bytes) {
    char* p = ws + off;
    off += (bytes + 255) & ~(size_t)255;
    return p;
  };
  unsigned short* Aln = (unsigned short*)carve(2048ull * 2048 * 2);       // 8 MB
  unsigned short* Wc  = (unsigned short*)carve(4ull * 2048 * 2048 * 2);   // 32 MB
  float*          bc  = (float*)carve(4ull * 2048 * 4);                   // 32 KB
  float*          Cqkv= (float*)carve(2048ull * 6144 * 4);                // 48 MB
  unsigned short* Qp  = (unsigned short*)carve(4194304ull * 2);           // 8 MB
  unsigned short* Kp  = (unsigned short*)carve(16777216ull * 2);          // 32 MB
  unsigned short* Vt  = (unsigned short*)carve(16777216ull * 2);          // 32 MB
  unsigned short* Ao  = (unsigned short*)carve(2048ull * 2048 * 2);       // 8 MB

  // output chunk offsets (floats)
  float* out_Kre = out + 4194304;
  float* out_Kim = out + 4194304 + 8388608;
  float* out_Vre = out + 4194304 + 2 * 8388608;
  float* out_Vim = out + 4194304 + 3 * 8388608;

  hipLaunchKernelGGL(ln_kernel, dim3(2048), dim3(256), 0, stream,
                     hre, him, gamma, bre, bim, Aln);
  hipLaunchKernelGGL(wprep_kernel, dim3(8192), dim3(256), 0, stream,
                     qWr, qWi, kWr, kWi, vWr, vWi, oWr, oWi, Wc);
  hipLaunchKernelGGL(bprep_kernel, dim3(32), dim3(256), 0, stream,
                     qbr, qbi, kbr, kbi, vbr, vbi, obr, obi, bc);
  // fused QKV GEMM: A=Aln (2048x2048), B=Wc rows 0..6143, C=Cqkv (2048x6144)
  hipLaunchKernelGGL(gemm_bt_kernel, dim3(48, 16), dim3(256), 0, stream,
                     Aln, Wc, bc, Cqkv, 6144, 2048);
  hipLaunchKernelGGL(pack_q_kernel, dim3(4096), dim3(256), 0, stream, Cqkv, Qp);
  hipLaunchKernelGGL(pack_kv_kernel, dim3(16384), dim3(256), 0, stream,
                     Kcr, Kci, Cqkv, 2048, Kp, out_Kre, out_Kim);
  hipLaunchKernelGGL(pack_kv_kernel, dim3(16384), dim3(256), 0, stream,
                     Vcr, Vci, Cqkv, 4096, (unsigned short*)nullptr, out_Vre, out_Vim);
  hipLaunchKernelGGL(pack_vt_kernel, dim3(16384), dim3(256), 0, stream,
                     Vcr, Vci, Cqkv, Vt);
  hipLaunchKernelGGL(attn_kernel, dim3(16, 32), dim3(256), 0, stream,
                     Qp, Kp, Vt, Ao);
  hipLaunchKernelGGL(gemm_oproj_kernel, dim3(16, 16), dim3(256), 0, stream,
                     Ao, Wc + 3ull * 2048 * 2048, bc + 3 * 2048, hre, him, out);
}

// Round 2
// 815.304 us; speedup vs baseline: 1.0415x; 1.0415x over previous
//
#include <hip/hip_runtime.h>
#include <hip/hip_bf16.h>
#include <cstdint>
#include <cstddef>

// ---------- types ----------
typedef __bf16 bf16x8 __attribute__((ext_vector_type(8)));
typedef float  f32x4  __attribute__((ext_vector_type(4)));

__device__ __forceinline__ unsigned short f2bf(float f) {
  union { float f; unsigned u; } v; v.f = f;
  unsigned u = v.u;
  u += 0x7FFFu + ((u >> 16) & 1u);   // RNE
  return (unsigned short)(u >> 16);
}

struct alignas(16) US8 { unsigned short u[8]; };

// sizes
#define BB 2
#define SS 1024
#define HID 1024
#define NHH 16
#define HDD 64
#define TT 4096
#define CCH 3072

// ---------- LayerNorm (complex) -> Aln bf16 [2048][2048] = [nr | ni] ----------
__global__ __launch_bounds__(256) void ln_kernel(
    const float* __restrict__ hre, const float* __restrict__ him,
    const float* __restrict__ gamma, const float* __restrict__ bre,
    const float* __restrict__ bim, unsigned short* __restrict__ Aln)
{
  int m = blockIdx.x;
  int tid = threadIdx.x;
  const float4 vr = ((const float4*)(hre + (size_t)m * HID))[tid];
  const float4 vi = ((const float4*)(him + (size_t)m * HID))[tid];
  float sr = vr.x + vr.y + vr.z + vr.w;
  float si = vi.x + vi.y + vi.z + vi.w;
  float sq = vr.x*vr.x + vr.y*vr.y + vr.z*vr.z + vr.w*vr.w
           + vi.x*vi.x + vi.y*vi.y + vi.z*vi.z + vi.w*vi.w;
  __shared__ float red[3][4];
  int lane = tid & 63, w = tid >> 6;
  for (int off = 32; off; off >>= 1) {
    sr += __shfl_down(sr, off, 64);
    si += __shfl_down(si, off, 64);
    sq += __shfl_down(sq, off, 64);
  }
  if (lane == 0) { red[0][w] = sr; red[1][w] = si; red[2][w] = sq; }
  __syncthreads();
  sr = red[0][0] + red[0][1] + red[0][2] + red[0][3];
  si = red[1][0] + red[1][1] + red[1][2] + red[1][3];
  sq = red[2][0] + red[2][1] + red[2][2] + red[2][3];
  float mur = sr * (1.f/1024.f), mui = si * (1.f/1024.f);
  float var = sq * (1.f/1024.f) - mur*mur - mui*mui;
  float inv = rsqrtf(var + 1e-5f);
  int k = tid * 4;
  float4 g  = ((const float4*)gamma)[tid];
  float4 br = ((const float4*)bre)[tid];
  float4 bi = ((const float4*)bim)[tid];
  ushort4 nr, ni;
  nr.x = f2bf((vr.x - mur) * inv * g.x + br.x);
  nr.y = f2bf((vr.y - mur) * inv * g.y + br.y);
  nr.z = f2bf((vr.z - mur) * inv * g.z + br.z);
  nr.w = f2bf((vr.w - mur) * inv * g.w + br.w);
  ni.x = f2bf((vi.x - mui) * inv * g.x + bi.x);
  ni.y = f2bf((vi.y - mui) * inv * g.y + bi.y);
  ni.z = f2bf((vi.z - mui) * inv * g.z + bi.z);
  ni.w = f2bf((vi.w - mui) * inv * g.w + bi.w);
  *(ushort4*)&Aln[(size_t)m * 2048 + k]        = nr;
  *(ushort4*)&Aln[(size_t)m * 2048 + 1024 + k] = ni;
}

// ---------- combined weights: Wc[p][n][k] bf16, p in {q,k,v,o}, 2048x2048 each ----------
__global__ __launch_bounds__(256) void wprep_kernel(
    const float* __restrict__ qWr, const float* __restrict__ qWi,
    const float* __restrict__ kWr, const float* __restrict__ kWi,
    const float* __restrict__ vWr, const float* __restrict__ vWi,
    const float* __restrict__ oWr, const float* __restrict__ oWi,
    unsigned short* __restrict__ Wc)
{
  int gid = blockIdx.x * 256 + threadIdx.x;
  int idx = gid * 8;                     // over 4*2048*2048
  int p   = idx >> 22;
  int rem = idx & 0x3FFFFF;
  int n   = rem >> 11;
  int k   = rem & 2047;
  const float* Wr; const float* Wi;
  switch (p) {
    case 0:  Wr = qWr; Wi = qWi; break;
    case 1:  Wr = kWr; Wi = kWi; break;
    case 2:  Wr = vWr; Wi = vWi; break;
    default: Wr = oWr; Wi = oWi; break;
  }
  const float* src; float sgn = 1.f;
  if (n < 1024) {
    if (k < 1024) src = Wr + (size_t)n * 1024 + k;
    else        { src = Wi + (size_t)n * 1024 + (k - 1024); sgn = -1.f; }
  } else {
    if (k < 1024) src = Wi + (size_t)(n - 1024) * 1024 + k;
    else          src = Wr + (size_t)(n - 1024) * 1024 + (k - 1024);
  }
  float4 a = ((const float4*)src)[0];
  float4 b = ((const float4*)src)[1];
  US8 o;
  o.u[0] = f2bf(a.x * sgn); o.u[1] = f2bf(a.y * sgn);
  o.u[2] = f2bf(a.z * sgn); o.u[3] = f2bf(a.w * sgn);
  o.u[4] = f2bf(b.x * sgn); o.u[5] = f2bf(b.y * sgn);
  o.u[6] = f2bf(b.z * sgn); o.u[7] = f2bf(b.w * sgn);
  *(US8*)&Wc[idx] = o;
}

__global__ __launch_bounds__(256) void bprep_kernel(
    const float* __restrict__ qbr, const float* __restrict__ qbi,
    const float* __restrict__ kbr, const float* __restrict__ kbi,
    const float* __restrict__ vbr, const float* __restrict__ vbi,
    const float* __restrict__ obr, const float* __restrict__ obi,
    float* __restrict__ bc)
{
  int idx = blockIdx.x * 256 + threadIdx.x;  // 8192
  int p = idx >> 11, n = idx & 2047;
  const float* br; const float* bi;
  switch (p) {
    case 0:  br = qbr; bi = qbi; break;
    case 1:  br = kbr; bi = kbi; break;
    case 2:  br = vbr; bi = vbi; break;
    default: br = obr; bi = obi; break;
  }
  bc[idx] = (n < 1024) ? br[n] : bi[n - 1024];
}

// ---------- GEMM: C[M x N] = A[M x K] * B[N x K]^T + bias[n], bf16 in, f32 out ----------
__global__ __launch_bounds__(256) void gemm_bt_kernel(
    const unsigned short* __restrict__ A, const unsigned short* __restrict__ Bm,
    const float* __restrict__ bias, float* __restrict__ C, int Nstride, int K)
{
  __shared__ alignas(16) unsigned short As[128][32];
  __shared__ alignas(16) unsigned short Bs[128][32];
  int bm = blockIdx.y * 128;
  int bn = blockIdx.x * 128;
  int tid = threadIdx.x;
  int lane = tid & 63, w = tid >> 6;
  int wm = (w >> 1) * 64, wn = (w & 1) * 64;
  int l15 = lane & 15, q = lane >> 4;
  int lr = tid >> 2;            // 0..63
  int lc = (tid & 3) * 8;       // 0,8,16,24

  f32x4 acc[4][4] = {};

  for (int k0 = 0; k0 < K; k0 += 32) {
    *(float4*)&As[lr][lc]    = *(const float4*)&A [(size_t)(bm + lr)      * K + k0 + lc];
    *(float4*)&As[lr+64][lc] = *(const float4*)&A [(size_t)(bm + lr + 64) * K + k0 + lc];
    *(float4*)&Bs[lr][lc]    = *(const float4*)&Bm[(size_t)(bn + lr)      * K + k0 + lc];
    *(float4*)&Bs[lr+64][lc] = *(const float4*)&Bm[(size_t)(bn + lr + 64) * K + k0 + lc];
    __syncthreads();
    bf16x8 af[4], bfr[4];
#pragma unroll
    for (int i = 0; i < 4; i++) af[i]  = *(const bf16x8*)&As[wm + i*16 + l15][q*8];
#pragma unroll
    for (int i = 0; i < 4; i++) bfr[i] = *(const bf16x8*)&Bs[wn + i*16 + l15][q*8];
#pragma unroll
    for (int i = 0; i < 4; i++)
#pragma unroll
      for (int j = 0; j < 4; j++)
        acc[i][j] = __builtin_amdgcn_mfma_f32_16x16x32_bf16(af[i], bfr[j], acc[i][j], 0, 0, 0);
    __syncthreads();
  }

#pragma unroll
  for (int i = 0; i < 4; i++)
#pragma unroll
    for (int j = 0; j < 4; j++) {
      int n = bn + wn + j*16 + l15;
      float bv = bias[n];
#pragma unroll
      for (int r = 0; r < 4; r++) {
        int m = bm + wm + i*16 + q*4 + r;
        C[(size_t)m * Nstride + n] = acc[i][j][r] + bv;
      }
    }
}

// ---------- o-proj GEMM with residual + split write to out_re/out_im ----------
__global__ __launch_bounds__(256) void gemm_oproj_kernel(
    const unsigned short* __restrict__ A, const unsigned short* __restrict__ Bm,
    const float* __restrict__ bias, const float* __restrict__ hre,
    const float* __restrict__ him, float* __restrict__ out)
{
  __shared__ alignas(16) unsigned short As[128][32];
  __shared__ alignas(16) unsigned short Bs[128][32];
  int bm = blockIdx.y * 128;
  int bn = blockIdx.x * 128;
  int tid = threadIdx.x;
  int lane = tid & 63, w = tid >> 6;
  int wm = (w >> 1) * 64, wn = (w & 1) * 64;
  int l15 = lane & 15, q = lane >> 4;
  int lr = tid >> 2;
  int lc = (tid & 3) * 8;
  const int K = 2048;

  f32x4 acc[4][4] = {};

  for (int k0 = 0; k0 < K; k0 += 32) {
    *(float4*)&As[lr][lc]    = *(const float4*)&A [(size_t)(bm + lr)      * K + k0 + lc];
    *(float4*)&As[lr+64][lc] = *(const float4*)&A [(size_t)(bm + lr + 64) * K + k0 + lc];
    *(float4*)&Bs[lr][lc]    = *(const float4*)&Bm[(size_t)(bn + lr)      * K + k0 + lc];
    *(float4*)&Bs[lr+64][lc] = *(const float4*)&Bm[(size_t)(bn + lr + 64) * K + k0 + lc];
    __syncthreads();
    bf16x8 af[4], bfr[4];
#pragma unroll
    for (int i = 0; i < 4; i++) af[i]  = *(const bf16x8*)&As[wm + i*16 + l15][q*8];
#pragma unroll
    for (int i = 0; i < 4; i++) bfr[i] = *(const bf16x8*)&Bs[wn + i*16 + l15][q*8];
#pragma unroll
    for (int i = 0; i < 4; i++)
#pragma unroll
      for (int j = 0; j < 4; j++)
        acc[i][j] = __builtin_amdgcn_mfma_f32_16x16x32_bf16(af[i], bfr[j], acc[i][j], 0, 0, 0);
    __syncthreads();
  }

#pragma unroll
  for (int i = 0; i < 4; i++)
#pragma unroll
    for (int j = 0; j < 4; j++) {
      int n = bn + wn + j*16 + l15;
      float bv = bias[n];
#pragma unroll
      for (int r = 0; r < 4; r++) {
        int m = bm + wm + i*16 + q*4 + r;
        float val = acc[i][j][r] + bv;
        if (n < 1024) out[(size_t)m * 1024 + n] = val + hre[(size_t)m * 1024 + n];
        else out[2097152 + (size_t)m * 1024 + (n - 1024)] = val + him[(size_t)m * 1024 + (n - 1024)];
      }
    }
}

// ---------- pack Q: Cqkv cols [0,2048) -> Qp[bh][s][128] bf16, scaled by 1/8 ----------
__global__ __launch_bounds__(256) void pack_q_kernel(
    const float* __restrict__ Cqkv, unsigned short* __restrict__ Qp)
{
  int gid = blockIdx.x * 256 + threadIdx.x;
  int idx = gid * 4;                 // over 2*16*1024*128 = 4,194,304
  int d2 = idx & 127;
  int s  = (idx >> 7) & 1023;
  int bh = idx >> 17;
  int b = bh >> 4, h = bh & 15;
  int d = d2 & 63;
  int col = (d2 < 64) ? (h*64 + d) : (1024 + h*64 + d);
  float4 v = *(const float4*)&Cqkv[((size_t)b * 1024 + s) * 6144 + col];
  ushort4 o;
  o.x = f2bf(v.x * 0.125f); o.y = f2bf(v.y * 0.125f);
  o.z = f2bf(v.z * 0.125f); o.w = f2bf(v.w * 0.125f);
  *(ushort4*)&Qp[idx] = o;
}

// ---------- pack K or V: cache + Cqkv -> packed bf16 [bh][t][128] (optional) + new_* f32 outputs ----------
__global__ __launch_bounds__(256) void pack_kv_kernel(
    const float* __restrict__ c_re, const float* __restrict__ c_im,
    const float* __restrict__ Cqkv, int colbase,
    unsigned short* __restrict__ Kp,
    float* __restrict__ out_re, float* __restrict__ out_im)
{
  int gid = blockIdx.x * 256 + threadIdx.x;
  int idx = gid * 4;                 // over 2*16*4096*128 = 16,777,216
  int d2 = idx & 127;
  int t  = (idx >> 7) & 4095;
  int bh = idx >> 19;
  int b = bh >> 4, h = bh & 15;
  int d = d2 & 63;
  bool im = d2 >= 64;
  float4 v;
  if (t < CCH) {
    const float* src = im ? c_im : c_re;
    v = *(const float4*)&src[(((size_t)b * CCH + t) * 16 + h) * 64 + d];
  } else {
    int col = colbase + (im ? (1024 + h*64 + d) : (h*64 + d));
    v = *(const float4*)&Cqkv[((size_t)b * 1024 + (t - CCH)) * 6144 + col];
  }
  if (Kp) {
    ushort4 o;
    o.x = f2bf(v.x); o.y = f2bf(v.y); o.z = f2bf(v.z); o.w = f2bf(v.w);
    *(ushort4*)&Kp[idx] = o;
  }
  float* dst = im ? out_im : out_re;
  *(float4*)&dst[(((size_t)b * 4096 + t) * 16 + h) * 64 + d] = v;
}

// ---------- pack V transposed: Vt[bh][d2][t] bf16 ----------
__global__ __launch_bounds__(256) void pack_vt_kernel(
    const float* __restrict__ Vc_re, const float* __restrict__ Vc_im,
    const float* __restrict__ Cqkv, unsigned short* __restrict__ Vt)
{
  int gid = blockIdx.x * 256 + threadIdx.x;
  int idx = gid * 4;                 // over 2*16*128*4096 = 16,777,216
  int t4 = idx & 4095;
  int d2 = (idx >> 12) & 127;
  int bh = idx >> 19;
  int b = bh >> 4, h = bh & 15;
  int d = d2 & 63;
  const float* Vc = (d2 < 64) ? Vc_re : Vc_im;
  int colq = 4096 + ((d2 < 64) ? (h*64 + d) : (1024 + h*64 + d));
  ushort4 o;
  unsigned short ov[4];
#pragma unroll
  for (int j = 0; j < 4; j++) {
    int t = t4 + j;
    float val;
    if (t < CCH) val = Vc[(((size_t)b * CCH + t) * 16 + h) * 64 + d];
    else         val = Cqkv[((size_t)b * 1024 + (t - CCH)) * 6144 + colq];
    ov[j] = f2bf(val);
  }
  o.x = ov[0]; o.y = ov[1]; o.z = ov[2]; o.w = ov[3];
  *(ushort4*)&Vt[idx] = o;
}

// ---------- flash attention v2: 128 q-rows per wg, 64-t tiles, no online max ----------
// Qp [bh][s][128] (pre-scaled 1/8), Kp [bh][t][128], Vt [bh][d2][t]; out Ao bf16 [m][n]
__global__ __launch_bounds__(256) void attn_kernel(
    const unsigned short* __restrict__ Qp, const unsigned short* __restrict__ Kp,
    const unsigned short* __restrict__ Vt, unsigned short* __restrict__ Ao)
{
  const int s0 = blockIdx.x * 128;
  const int bh = blockIdx.y;
  const int b = bh >> 4, h = bh & 15;
  const int tid = threadIdx.x;
  const int lane = tid & 63, w = tid >> 6;
  const int l15 = lane & 15, q = lane >> 4;

  __shared__ alignas(16) unsigned short Ks[64][136];   // [t'][d2], pad 8
  __shared__ alignas(16) unsigned short Vs[128][72];   // [d2][t'], pad 8
  __shared__ alignas(16) unsigned short Ps[4][32][72]; // per-wave [row][t'], pad 8

  // persistent Q fragments: 2 m-frags x 4 kc
  bf16x8 qf[2][4];
#pragma unroll
  for (int mi = 0; mi < 2; mi++) {
    const size_t qb = ((size_t)bh * 1024 + s0 + w*32 + mi*16 + l15) * 128;
#pragma unroll
    for (int kc = 0; kc < 4; kc++)
      qf[mi][kc] = *(const bf16x8*)&Qp[qb + kc*32 + q*8];
  }

  f32x4 oacc[2][8] = {};
  float lsum[2][4] = {};

  const size_t kpb = (size_t)bh * 4096 * 128;
  const size_t vtb = (size_t)bh * 128 * 4096;

  const int kr = tid >> 2, kc4 = (tid & 3) * 32;   // K staging: row, col base (el)
  const int vr = tid >> 1, vc4 = (tid & 1) * 32;   // V staging: row, col base (el)

  const int n_tiles = (s0 + 3200) >> 6;   // 50 + 2*bx
  const int n_safe  = n_tiles - 2;        // last 2 tiles need masking

  float4 kreg[4], vreg[4];
  {
    const unsigned short* kp = &Kp[kpb + (size_t)kr * 128 + kc4];
    kreg[0] = *(const float4*)(kp);      kreg[1] = *(const float4*)(kp + 8);
    kreg[2] = *(const float4*)(kp + 16); kreg[3] = *(const float4*)(kp + 24);
    const unsigned short* vp = &Vt[vtb + (size_t)vr * 4096 + vc4];
    vreg[0] = *(const float4*)(vp);      vreg[1] = *(const float4*)(vp + 8);
    vreg[2] = *(const float4*)(vp + 16); vreg[3] = *(const float4*)(vp + 24);
  }

  for (int it = 0; it < n_tiles; it++) {
    // commit staged regs to LDS
    *(float4*)&Ks[kr][kc4]      = kreg[0];
    *(float4*)&Ks[kr][kc4 + 8]  = kreg[1];
    *(float4*)&Ks[kr][kc4 + 16] = kreg[2];
    *(float4*)&Ks[kr][kc4 + 24] = kreg[3];
    *(float4*)&Vs[vr][vc4]      = vreg[0];
    *(float4*)&Vs[vr][vc4 + 8]  = vreg[1];
    *(float4*)&Vs[vr][vc4 + 16] = vreg[2];
    *(float4*)&Vs[vr][vc4 + 24] = vreg[3];
    __syncthreads();

    // prefetch next tile while computing this one
    if (it + 1 < n_tiles) {
      const int t1 = (it + 1) << 6;
      const unsigned short* kp = &Kp[kpb + (size_t)(t1 + kr) * 128 + kc4];
      kreg[0] = *(const float4*)(kp);      kreg[1] = *(const float4*)(kp + 8);
      kreg[2] = *(const float4*)(kp + 16); kreg[3] = *(const float4*)(kp + 24);
      const unsigned short* vp = &Vt[vtb + (size_t)vr * 4096 + t1 + vc4];
      vreg[0] = *(const float4*)(vp);      vreg[1] = *(const float4*)(vp + 8);
      vreg[2] = *(const float4*)(vp + 16); vreg[3] = *(const float4*)(vp + 24);
    }

    // QK^T: sacc[mi][nc] over 4 k-chunks
    f32x4 sacc[2][4] = {};
#pragma unroll
    for (int kc = 0; kc < 4; kc++) {
      bf16x8 kf[4];
#pragma unroll
      for (int nc = 0; nc < 4; nc++)
        kf[nc] = *(const bf16x8*)&Ks[nc*16 + l15][kc*32 + q*8];
#pragma unroll
      for (int mi = 0; mi < 2; mi++)
#pragma unroll
        for (int nc = 0; nc < 4; nc++)
          sacc[mi][nc] = __builtin_amdgcn_mfma_f32_16x16x32_bf16(qf[mi][kc], kf[nc], sacc[mi][nc], 0, 0, 0);
    }

    // exp (no max subtraction; scores bounded) + mask on last 2 tiles
    if (it < n_safe) {
#pragma unroll
      for (int mi = 0; mi < 2; mi++)
#pragma unroll
        for (int r = 0; r < 4; r++) {
          float ls = 0.f;
#pragma unroll
          for (int nc = 0; nc < 4; nc++) {
            float p = __expf(sacc[mi][nc][r]);
            ls += p;
            Ps[w][mi*16 + q*4 + r][nc*16 + l15] = f2bf(p);
          }
          lsum[mi][r] += ls;
        }
    } else {
      const int t0 = it << 6;
#pragma unroll
      for (int mi = 0; mi < 2; mi++)
#pragma unroll
        for (int r = 0; r < 4; r++) {
          const int rel = s0 + w*32 + mi*16 + q*4 + r + CCH - t0;  // allowed t' <= rel
          float ls = 0.f;
#pragma unroll
          for (int nc = 0; nc < 4; nc++) {
            float p = (nc*16 + l15 <= rel) ? __expf(sacc[mi][nc][r]) : 0.f;
            ls += p;
            Ps[w][mi*16 + q*4 + r][nc*16 + l15] = f2bf(p);
          }
          lsum[mi][r] += ls;
        }
    }

    // PV: O += P * V   (P from per-wave LDS, no barrier needed)
#pragma unroll
    for (int kch = 0; kch < 2; kch++) {
      bf16x8 pf[2];
#pragma unroll
      for (int mi = 0; mi < 2; mi++)
        pf[mi] = *(const bf16x8*)&Ps[w][mi*16 + l15][kch*32 + q*8];
#pragma unroll
      for (int dc = 0; dc < 8; dc++) {
        bf16x8 vfr = *(const bf16x8*)&Vs[dc*16 + l15][kch*32 + q*8];
#pragma unroll
        for (int mi = 0; mi < 2; mi++)
          oacc[mi][dc] = __builtin_amdgcn_mfma_f32_16x16x32_bf16(pf[mi], vfr, oacc[mi][dc], 0, 0, 0);
      }
    }
    __syncthreads();
  }

  // normalize and write
  float linv[2][4];
#pragma unroll
  for (int mi = 0; mi < 2; mi++)
#pragma unroll
    for (int r = 0; r < 4; r++) {
      float l = lsum[mi][r];
      l += __shfl_xor(l, 1, 64);
      l += __shfl_xor(l, 2, 64);
      l += __shfl_xor(l, 4, 64);
      l += __shfl_xor(l, 8, 64);
      linv[mi][r] = 1.f / l;
    }

#pragma unroll
  for (int mi = 0; mi < 2; mi++)
#pragma unroll
    for (int dc = 0; dc < 8; dc++)
#pragma unroll
      for (int r = 0; r < 4; r++) {
        int s = s0 + w*32 + mi*16 + q*4 + r;
        int d2 = dc*16 + l15;
        float val = oacc[mi][dc][r] * linv[mi][r];
        int m = b * 1024 + s;
        int n = (d2 < 64) ? (h*64 + d2) : (1024 + h*64 + (d2 - 64));
        Ao[(size_t)m * 2048 + n] = f2bf(val);
      }
}

// ---------- launch ----------
extern "C" void kernel_launch(void* const* d_in, const int* in_sizes, int n_in,
                              void* d_out, int out_size, void* d_ws, size_t ws_size,
                              hipStream_t stream)
{
  (void)in_sizes; (void)n_in; (void)out_size; (void)ws_size;
  const float* hre = (const float*)d_in[0];
  const float* him = (const float*)d_in[1];
  const float* Kcr = (const float*)d_in[2];
  const float* Kci = (const float*)d_in[3];
  const float* Vcr = (const float*)d_in[4];
  const float* Vci = (const float*)d_in[5];
  const float* gamma = (const float*)d_in[6];
  const float* bre = (const float*)d_in[7];
  const float* bim = (const float*)d_in[8];
  const float* qWr = (const float*)d_in[9];
  const float* qWi = (const float*)d_in[10];
  const float* qbr = (const float*)d_in[11];
  const float* qbi = (const float*)d_in[12];
  const float* kWr = (const float*)d_in[13];
  const float* kWi = (const float*)d_in[14];
  const float* kbr = (const float*)d_in[15];
  const float* kbi = (const float*)d_in[16];
  const float* vWr = (const float*)d_in[17];
  const float* vWi = (const float*)d_in[18];
  const float* vbr = (const float*)d_in[19];
  const float* vbi = (const float*)d_in[20];
  const float* oWr = (const float*)d_in[21];
  const float* oWi = (const float*)d_in[22];
  const float* obr = (const float*)d_in[23];
  const float* obi = (const float*)d_in[24];
  float* out = (float*)d_out;

  char* ws = (char*)d_ws;
  size_t off = 0;
  auto carve = [&](size_t bytes) {
    char* p = ws + off;
    off += (bytes + 255) & ~(size_t)255;
    return p;
  };
  unsigned short* Aln = (unsigned short*)carve(2048ull * 2048 * 2);       // 8 MB
  unsigned short* Wc  = (unsigned short*)carve(4ull * 2048 * 2048 * 2);   // 32 MB
  float*          bc  = (float*)carve(4ull * 2048 * 4);                   // 32 KB
  float*          Cqkv= (float*)carve(2048ull * 6144 * 4);                // 48 MB
  unsigned short* Qp  = (unsigned short*)carve(4194304ull * 2);           // 8 MB
  unsigned short* Kp  = (unsigned short*)carve(16777216ull * 2);          // 32 MB
  unsigned short* Vt  = (unsigned short*)carve(16777216ull * 2);          // 32 MB
  unsigned short* Ao  = (unsigned short*)carve(2048ull * 2048 * 2);       // 8 MB

  // output chunk offsets (floats)
  float* out_Kre = out + 4194304;
  float* out_Kim = out + 4194304 + 8388608;
  float* out_Vre = out + 4194304 + 2 * 8388608;
  float* out_Vim = out + 4194304 + 3 * 8388608;

  hipLaunchKernelGGL(ln_kernel, dim3(2048), dim3(256), 0, stream,
                     hre, him, gamma, bre, bim, Aln);
  hipLaunchKernelGGL(wprep_kernel, dim3(8192), dim3(256), 0, stream,
                     qWr, qWi, kWr, kWi, vWr, vWi, oWr, oWi, Wc);
  hipLaunchKernelGGL(bprep_kernel, dim3(32), dim3(256), 0, stream,
                     qbr, qbi, kbr, kbi, vbr, vbi, obr, obi, bc);
  hipLaunchKernelGGL(gemm_bt_kernel, dim3(48, 16), dim3(256), 0, stream,
                     Aln, Wc, bc, Cqkv, 6144, 2048);
  hipLaunchKernelGGL(pack_q_kernel, dim3(4096), dim3(256), 0, stream, Cqkv, Qp);
  hipLaunchKernelGGL(pack_kv_kernel, dim3(16384), dim3(256), 0, stream,
                     Kcr, Kci, Cqkv, 2048, Kp, out_Kre, out_Kim);
  hipLaunchKernelGGL(pack_kv_kernel, dim3(16384), dim3(256), 0, stream,
                     Vcr, Vci, Cqkv, 4096, (unsigned short*)nullptr, out_Vre, out_Vim);
  hipLaunchKernelGGL(pack_vt_kernel, dim3(16384), dim3(256), 0, stream,
                     Vcr, Vci, Cqkv, Vt);
  hipLaunchKernelGGL(attn_kernel, dim3(8, 32), dim3(256), 0, stream,
                     Qp, Kp, Vt, Ao);
  hipLaunchKernelGGL(gemm_oproj_kernel, dim3(16, 16), dim3(256), 0, stream,
                     Ao, Wc + 3ull * 2048 * 2048, bc + 3 * 2048, hre, him, out);
}

// Round 3
// 610.815 us; speedup vs baseline: 1.3902x; 1.3348x over previous
//
#include <hip/hip_runtime.h>
#include <hip/hip_bf16.h>
#include <cstdint>
#include <cstddef>

// ---------- types ----------
typedef __bf16 bf16x8 __attribute__((ext_vector_type(8)));
typedef float  f32x4  __attribute__((ext_vector_type(4)));

__device__ __forceinline__ unsigned short f2bf(float f) {
  union { float f; unsigned u; } v; v.f = f;
  unsigned u = v.u;
  u += 0x7FFFu + ((u >> 16) & 1u);   // RNE
  return (unsigned short)(u >> 16);
}

struct alignas(16) US8 { unsigned short u[8]; };

__device__ __forceinline__ void g2lds16(const void* g, void* l) {
  __builtin_amdgcn_global_load_lds(
      (const __attribute__((address_space(1))) unsigned int*)g,
      (__attribute__((address_space(3))) unsigned int*)l, 16, 0, 0);
}

// sizes
#define BB 2
#define SS 1024
#define HID 1024
#define NHH 16
#define HDD 64
#define TT 4096
#define CCH 3072

// ---------- LayerNorm (complex) -> Aln bf16 [2048][2048] = [nr | ni] ----------
__global__ __launch_bounds__(256) void ln_kernel(
    const float* __restrict__ hre, const float* __restrict__ him,
    const float* __restrict__ gamma, const float* __restrict__ bre,
    const float* __restrict__ bim, unsigned short* __restrict__ Aln)
{
  int m = blockIdx.x;
  int tid = threadIdx.x;
  const float4 vr = ((const float4*)(hre + (size_t)m * HID))[tid];
  const float4 vi = ((const float4*)(him + (size_t)m * HID))[tid];
  float sr = vr.x + vr.y + vr.z + vr.w;
  float si = vi.x + vi.y + vi.z + vi.w;
  float sq = vr.x*vr.x + vr.y*vr.y + vr.z*vr.z + vr.w*vr.w
           + vi.x*vi.x + vi.y*vi.y + vi.z*vi.z + vi.w*vi.w;
  __shared__ float red[3][4];
  int lane = tid & 63, w = tid >> 6;
  for (int off = 32; off; off >>= 1) {
    sr += __shfl_down(sr, off, 64);
    si += __shfl_down(si, off, 64);
    sq += __shfl_down(sq, off, 64);
  }
  if (lane == 0) { red[0][w] = sr; red[1][w] = si; red[2][w] = sq; }
  __syncthreads();
  sr = red[0][0] + red[0][1] + red[0][2] + red[0][3];
  si = red[1][0] + red[1][1] + red[1][2] + red[1][3];
  sq = red[2][0] + red[2][1] + red[2][2] + red[2][3];
  float mur = sr * (1.f/1024.f), mui = si * (1.f/1024.f);
  float var = sq * (1.f/1024.f) - mur*mur - mui*mui;
  float inv = rsqrtf(var + 1e-5f);
  int k = tid * 4;
  float4 g  = ((const float4*)gamma)[tid];
  float4 br = ((const float4*)bre)[tid];
  float4 bi = ((const float4*)bim)[tid];
  ushort4 nr, ni;
  nr.x = f2bf((vr.x - mur) * inv * g.x + br.x);
  nr.y = f2bf((vr.y - mur) * inv * g.y + br.y);
  nr.z = f2bf((vr.z - mur) * inv * g.z + br.z);
  nr.w = f2bf((vr.w - mur) * inv * g.w + br.w);
  ni.x = f2bf((vi.x - mui) * inv * g.x + bi.x);
  ni.y = f2bf((vi.y - mui) * inv * g.y + bi.y);
  ni.z = f2bf((vi.z - mui) * inv * g.z + bi.z);
  ni.w = f2bf((vi.w - mui) * inv * g.w + bi.w);
  *(ushort4*)&Aln[(size_t)m * 2048 + k]        = nr;
  *(ushort4*)&Aln[(size_t)m * 2048 + 1024 + k] = ni;
}

// ---------- combined weights: Wc[p][n][k] bf16, p in {q,k,v,o}, 2048x2048 each ----------
__global__ __launch_bounds__(256) void wprep_kernel(
    const float* __restrict__ qWr, const float* __restrict__ qWi,
    const float* __restrict__ kWr, const float* __restrict__ kWi,
    const float* __restrict__ vWr, const float* __restrict__ vWi,
    const float* __restrict__ oWr, const float* __restrict__ oWi,
    unsigned short* __restrict__ Wc)
{
  int gid = blockIdx.x * 256 + threadIdx.x;
  int idx = gid * 8;                     // over 4*2048*2048
  int p   = idx >> 22;
  int rem = idx & 0x3FFFFF;
  int n   = rem >> 11;
  int k   = rem & 2047;
  const float* Wr; const float* Wi;
  switch (p) {
    case 0:  Wr = qWr; Wi = qWi; break;
    case 1:  Wr = kWr; Wi = kWi; break;
    case 2:  Wr = vWr; Wi = vWi; break;
    default: Wr = oWr; Wi = oWi; break;
  }
  const float* src; float sgn = 1.f;
  if (n < 1024) {
    if (k < 1024) src = Wr + (size_t)n * 1024 + k;
    else        { src = Wi + (size_t)n * 1024 + (k - 1024); sgn = -1.f; }
  } else {
    if (k < 1024) src = Wi + (size_t)(n - 1024) * 1024 + k;
    else          src = Wr + (size_t)(n - 1024) * 1024 + (k - 1024);
  }
  float4 a = ((const float4*)src)[0];
  float4 b = ((const float4*)src)[1];
  US8 o;
  o.u[0] = f2bf(a.x * sgn); o.u[1] = f2bf(a.y * sgn);
  o.u[2] = f2bf(a.z * sgn); o.u[3] = f2bf(a.w * sgn);
  o.u[4] = f2bf(b.x * sgn); o.u[5] = f2bf(b.y * sgn);
  o.u[6] = f2bf(b.z * sgn); o.u[7] = f2bf(b.w * sgn);
  *(US8*)&Wc[idx] = o;
}

__global__ __launch_bounds__(256) void bprep_kernel(
    const float* __restrict__ qbr, const float* __restrict__ qbi,
    const float* __restrict__ kbr, const float* __restrict__ kbi,
    const float* __restrict__ vbr, const float* __restrict__ vbi,
    const float* __restrict__ obr, const float* __restrict__ obi,
    float* __restrict__ bc)
{
  int idx = blockIdx.x * 256 + threadIdx.x;  // 8192
  int p = idx >> 11, n = idx & 2047;
  const float* br; const float* bi;
  switch (p) {
    case 0:  br = qbr; bi = qbi; break;
    case 1:  br = kbr; bi = kbi; break;
    case 2:  br = vbr; bi = vbi; break;
    default: br = obr; bi = obi; break;
  }
  bc[idx] = (n < 1024) ? br[n] : bi[n - 1024];
}

// ---------- GEMM: C[M x N] = A[M x K] * B[N x K]^T + bias[n], bf16 in, f32 out ----------
__global__ __launch_bounds__(256) void gemm_bt_kernel(
    const unsigned short* __restrict__ A, const unsigned short* __restrict__ Bm,
    const float* __restrict__ bias, float* __restrict__ C, int Nstride, int K)
{
  __shared__ alignas(16) unsigned short As[128][32];
  __shared__ alignas(16) unsigned short Bs[128][32];
  int bm = blockIdx.y * 128;
  int bn = blockIdx.x * 128;
  int tid = threadIdx.x;
  int lane = tid & 63, w = tid >> 6;
  int wm = (w >> 1) * 64, wn = (w & 1) * 64;
  int l15 = lane & 15, q = lane >> 4;
  int lr = tid >> 2;            // 0..63
  int lc = (tid & 3) * 8;       // 0,8,16,24

  f32x4 acc[4][4] = {};

  for (int k0 = 0; k0 < K; k0 += 32) {
    *(float4*)&As[lr][lc]    = *(const float4*)&A [(size_t)(bm + lr)      * K + k0 + lc];
    *(float4*)&As[lr+64][lc] = *(const float4*)&A [(size_t)(bm + lr + 64) * K + k0 + lc];
    *(float4*)&Bs[lr][lc]    = *(const float4*)&Bm[(size_t)(bn + lr)      * K + k0 + lc];
    *(float4*)&Bs[lr+64][lc] = *(const float4*)&Bm[(size_t)(bn + lr + 64) * K + k0 + lc];
    __syncthreads();
    bf16x8 af[4], bfr[4];
#pragma unroll
    for (int i = 0; i < 4; i++) af[i]  = *(const bf16x8*)&As[wm + i*16 + l15][q*8];
#pragma unroll
    for (int i = 0; i < 4; i++) bfr[i] = *(const bf16x8*)&Bs[wn + i*16 + l15][q*8];
#pragma unroll
    for (int i = 0; i < 4; i++)
#pragma unroll
      for (int j = 0; j < 4; j++)
        acc[i][j] = __builtin_amdgcn_mfma_f32_16x16x32_bf16(af[i], bfr[j], acc[i][j], 0, 0, 0);
    __syncthreads();
  }

#pragma unroll
  for (int i = 0; i < 4; i++)
#pragma unroll
    for (int j = 0; j < 4; j++) {
      int n = bn + wn + j*16 + l15;
      float bv = bias[n];
#pragma unroll
      for (int r = 0; r < 4; r++) {
        int m = bm + wm + i*16 + q*4 + r;
        C[(size_t)m * Nstride + n] = acc[i][j][r] + bv;
      }
    }
}

// ---------- o-proj GEMM with residual + split write to out_re/out_im ----------
__global__ __launch_bounds__(256) void gemm_oproj_kernel(
    const unsigned short* __restrict__ A, const unsigned short* __restrict__ Bm,
    const float* __restrict__ bias, const float* __restrict__ hre,
    const float* __restrict__ him, float* __restrict__ out)
{
  __shared__ alignas(16) unsigned short As[128][32];
  __shared__ alignas(16) unsigned short Bs[128][32];
  int bm = blockIdx.y * 128;
  int bn = blockIdx.x * 128;
  int tid = threadIdx.x;
  int lane = tid & 63, w = tid >> 6;
  int wm = (w >> 1) * 64, wn = (w & 1) * 64;
  int l15 = lane & 15, q = lane >> 4;
  int lr = tid >> 2;
  int lc = (tid & 3) * 8;
  const int K = 2048;

  f32x4 acc[4][4] = {};

  for (int k0 = 0; k0 < K; k0 += 32) {
    *(float4*)&As[lr][lc]    = *(const float4*)&A [(size_t)(bm + lr)      * K + k0 + lc];
    *(float4*)&As[lr+64][lc] = *(const float4*)&A [(size_t)(bm + lr + 64) * K + k0 + lc];
    *(float4*)&Bs[lr][lc]    = *(const float4*)&Bm[(size_t)(bn + lr)      * K + k0 + lc];
    *(float4*)&Bs[lr+64][lc] = *(const float4*)&Bm[(size_t)(bn + lr + 64) * K + k0 + lc];
    __syncthreads();
    bf16x8 af[4], bfr[4];
#pragma unroll
    for (int i = 0; i < 4; i++) af[i]  = *(const bf16x8*)&As[wm + i*16 + l15][q*8];
#pragma unroll
    for (int i = 0; i < 4; i++) bfr[i] = *(const bf16x8*)&Bs[wn + i*16 + l15][q*8];
#pragma unroll
    for (int i = 0; i < 4; i++)
#pragma unroll
      for (int j = 0; j < 4; j++)
        acc[i][j] = __builtin_amdgcn_mfma_f32_16x16x32_bf16(af[i], bfr[j], acc[i][j], 0, 0, 0);
    __syncthreads();
  }

#pragma unroll
  for (int i = 0; i < 4; i++)
#pragma unroll
    for (int j = 0; j < 4; j++) {
      int n = bn + wn + j*16 + l15;
      float bv = bias[n];
#pragma unroll
      for (int r = 0; r < 4; r++) {
        int m = bm + wm + i*16 + q*4 + r;
        float val = acc[i][j][r] + bv;
        if (n < 1024) out[(size_t)m * 1024 + n] = val + hre[(size_t)m * 1024 + n];
        else out[2097152 + (size_t)m * 1024 + (n - 1024)] = val + him[(size_t)m * 1024 + (n - 1024)];
      }
    }
}

// ---------- pack Q: Cqkv cols [0,2048) -> Qp[bh][s][128] bf16, scaled by 1/8 ----------
__global__ __launch_bounds__(256) void pack_q_kernel(
    const float* __restrict__ Cqkv, unsigned short* __restrict__ Qp)
{
  int gid = blockIdx.x * 256 + threadIdx.x;
  int idx = gid * 4;                 // over 2*16*1024*128 = 4,194,304
  int d2 = idx & 127;
  int s  = (idx >> 7) & 1023;
  int bh = idx >> 17;
  int b = bh >> 4, h = bh & 15;
  int d = d2 & 63;
  int col = (d2 < 64) ? (h*64 + d) : (1024 + h*64 + d);
  float4 v = *(const float4*)&Cqkv[((size_t)b * 1024 + s) * 6144 + col];
  ushort4 o;
  o.x = f2bf(v.x * 0.125f); o.y = f2bf(v.y * 0.125f);
  o.z = f2bf(v.z * 0.125f); o.w = f2bf(v.w * 0.125f);
  *(ushort4*)&Qp[idx] = o;
}

// ---------- pack K or V: cache + Cqkv -> packed bf16 [bh][t][128] (optional) + new_* f32 outputs ----------
__global__ __launch_bounds__(256) void pack_kv_kernel(
    const float* __restrict__ c_re, const float* __restrict__ c_im,
    const float* __restrict__ Cqkv, int colbase,
    unsigned short* __restrict__ Kp,
    float* __restrict__ out_re, float* __restrict__ out_im)
{
  int gid = blockIdx.x * 256 + threadIdx.x;
  int idx = gid * 4;                 // over 2*16*4096*128 = 16,777,216
  int d2 = idx & 127;
  int t  = (idx >> 7) & 4095;
  int bh = idx >> 19;
  int b = bh >> 4, h = bh & 15;
  int d = d2 & 63;
  bool im = d2 >= 64;
  float4 v;
  if (t < CCH) {
    const float* src = im ? c_im : c_re;
    v = *(const float4*)&src[(((size_t)b * CCH + t) * 16 + h) * 64 + d];
  } else {
    int col = colbase + (im ? (1024 + h*64 + d) : (h*64 + d));
    v = *(const float4*)&Cqkv[((size_t)b * 1024 + (t - CCH)) * 6144 + col];
  }
  if (Kp) {
    ushort4 o;
    o.x = f2bf(v.x); o.y = f2bf(v.y); o.z = f2bf(v.z); o.w = f2bf(v.w);
    *(ushort4*)&Kp[idx] = o;
  }
  float* dst = im ? out_im : out_re;
  *(float4*)&dst[(((size_t)b * 4096 + t) * 16 + h) * 64 + d] = v;
}

// ---------- pack V transposed via LDS: Vt[bh][d2][t] bf16 ----------
__global__ __launch_bounds__(256) void pack_vt_kernel(
    const float* __restrict__ Vc_re, const float* __restrict__ Vc_im,
    const float* __restrict__ Cqkv, unsigned short* __restrict__ Vt)
{
  __shared__ float Ts[64][136];
  const int ty = blockIdx.x & 63;   // t-tile
  const int bh = blockIdx.x >> 6;   // 0..31
  const int b = bh >> 4, h = bh & 15;
  const int t0 = ty * 64;
  const int tid = threadIdx.x;
#pragma unroll
  for (int rr = 0; rr < 8; rr++) {
    int j = rr * 256 + tid;
    int t_loc = j >> 5, c = j & 31;
    int d2 = c * 4;
    int t = t0 + t_loc;
    float4 v;
    if (t < CCH) {
      const float* src = (d2 < 64) ? Vc_re : Vc_im;
      int d = (d2 < 64) ? d2 : d2 - 64;
      v = *(const float4*)&src[(((size_t)b * CCH + t) * 16 + h) * 64 + d];
    } else {
      int col = 4096 + ((d2 < 64) ? (h*64 + d2) : (1024 + h*64 + d2 - 64));
      v = *(const float4*)&Cqkv[((size_t)b * 1024 + (t - CCH)) * 6144 + col];
    }
    *(float4*)&Ts[t_loc][d2] = v;
  }
  __syncthreads();
  const int d2 = tid >> 1, half = tid & 1;
  unsigned short tmp[32];
#pragma unroll
  for (int i = 0; i < 32; i++) tmp[i] = f2bf(Ts[half*32 + i][d2]);
  size_t dst = (size_t)bh * 128 * 4096 + (size_t)d2 * 4096 + t0 + half*32;
#pragma unroll
  for (int kq = 0; kq < 4; kq++)
    *(US8*)&Vt[dst + kq*8] = *(US8*)&tmp[kq*8];
}

// ---------- flash attention v3: 128 q-rows/block, t-range split over 2 blocks,
// global_load_lds double-buffered staging, XOR-swizzled LDS, partial outputs ----------
// Qp [bh][s][128] (pre-scaled 1/8), Kp [bh][t][128], Vt [bh][d2][t]
// Opart [tpar][bh][s][128] f32, Lpart [tpar][bh][s] f32
__global__ __launch_bounds__(256) void attn_kernel(
    const unsigned short* __restrict__ Qp, const unsigned short* __restrict__ Kp,
    const unsigned short* __restrict__ Vt, float* __restrict__ Opart,
    float* __restrict__ Lpart)
{
  const int bh   = blockIdx.x;   // 0..31  (linear id % 8 == bh % 8 -> XCD locality)
  const int sblk = blockIdx.y;   // 0..7
  const int tpar = blockIdx.z;   // 0..1
  const int s0 = sblk * 128;
  const int tid = threadIdx.x;
  const int lane = tid & 63, w = tid >> 6;
  const int l15 = lane & 15, q = lane >> 4;

  __shared__ alignas(16) unsigned short Ks[2][64][128];  // 32 KB, chunk-swizzled
  __shared__ alignas(16) unsigned short Vs[2][128][64];  // 32 KB, chunk-swizzled
  __shared__ alignas(16) unsigned short Ps[4][32][64];   // 16 KB, chunk-swizzled

  // persistent Q fragments: 2 m-frags x 4 k-chunks
  bf16x8 qf[2][4];
#pragma unroll
  for (int mi = 0; mi < 2; mi++) {
    const size_t qb = ((size_t)bh * 1024 + s0 + w*32 + mi*16 + l15) * 128;
#pragma unroll
    for (int kc = 0; kc < 4; kc++)
      qf[mi][kc] = *(const bf16x8*)&Qp[qb + kc*32 + q*8];
  }

  f32x4 oacc[2][8] = {};
  float lsum[2][4] = {};

  const size_t kpb = (size_t)bh * 4096 * 128;
  const size_t vtb = (size_t)bh * 128 * 4096;
  const int n_tiles = 2*sblk + 50;
  const int n_safe  = n_tiles - 2;

  // async staging: 1024 16B-chunks per K tile and per V tile; each wave does 4+4
  auto issue = [&](int buf, int t0) {
#pragma unroll
    for (int kk = 0; kk < 4; kk++) {
      int j = (w*4 + kk)*64 + lane;          // chunk index
      int r = j >> 4, p = j & 15, c = p ^ (r & 7);
      g2lds16(&Kp[kpb + (size_t)(t0 + r) * 128 + c*8],
              (unsigned short*)&Ks[buf][0][0] + (size_t)j * 8);
    }
#pragma unroll
    for (int kk = 0; kk < 4; kk++) {
      int j = (w*4 + kk)*64 + lane;
      int r = j >> 3, p = j & 7, c = p ^ (r & 7);
      g2lds16(&Vt[vtb + (size_t)r * 4096 + t0 + c*8],
              (unsigned short*)&Vs[buf][0][0] + (size_t)j * 8);
    }
  };

  int buf = 0;
  issue(0, tpar * 64);

  for (int it = tpar; it < n_tiles; it += 2) {
    __syncthreads();                       // drains loads for `buf`
    if (it + 2 < n_tiles) issue(buf ^ 1, (it + 2) * 64);   // overlap with compute

    // QK^T
    f32x4 sacc[2][4] = {};
#pragma unroll
    for (int kc = 0; kc < 4; kc++) {
      bf16x8 kf[4];
#pragma unroll
      for (int nc = 0; nc < 4; nc++)
        kf[nc] = *(const bf16x8*)&Ks[buf][nc*16 + l15][((kc*4 + q) ^ (l15 & 7)) * 8];
#pragma unroll
      for (int mi = 0; mi < 2; mi++)
#pragma unroll
        for (int nc = 0; nc < 4; nc++)
          sacc[mi][nc] = __builtin_amdgcn_mfma_f32_16x16x32_bf16(qf[mi][kc], kf[nc], sacc[mi][nc], 0, 0, 0);
    }

    // exp + P store (swizzled), mask only last 2 tiles
    const bool safe = (it < n_safe);
    const int t0 = it << 6;
#pragma unroll
    for (int mi = 0; mi < 2; mi++)
#pragma unroll
      for (int r = 0; r < 4; r++) {
        const int rr = mi*16 + q*4 + r;
        const int rel = s0 + w*32 + rr + CCH - t0;
        float ls = 0.f;
#pragma unroll
        for (int nc = 0; nc < 4; nc++) {
          float p = __expf(sacc[mi][nc][r]);
          if (!safe && (nc*16 + l15 > rel)) p = 0.f;
          ls += p;
          int cch = ((nc*2 + (l15 >> 3)) ^ (rr & 7));
          Ps[w][rr][cch*8 + (l15 & 7)] = f2bf(p);
        }
        lsum[mi][r] += ls;
      }

    // PV
#pragma unroll
    for (int kch = 0; kch < 2; kch++) {
      bf16x8 pf[2];
#pragma unroll
      for (int mi = 0; mi < 2; mi++) {
        int rr = mi*16 + l15;
        pf[mi] = *(const bf16x8*)&Ps[w][rr][((kch*4 + q) ^ (rr & 7)) * 8];
      }
#pragma unroll
      for (int dc = 0; dc < 8; dc++) {
        int d2 = dc*16 + l15;
        bf16x8 vfr = *(const bf16x8*)&Vs[buf][d2][((kch*4 + q) ^ (l15 & 7)) * 8];
#pragma unroll
        for (int mi = 0; mi < 2; mi++)
          oacc[mi][dc] = __builtin_amdgcn_mfma_f32_16x16x32_bf16(pf[mi], vfr, oacc[mi][dc], 0, 0, 0);
      }
    }
    buf ^= 1;
  }

  // write partials
  const size_t pb = ((size_t)tpar * 32 + bh) * 1024 + s0 + w*32;
#pragma unroll
  for (int mi = 0; mi < 2; mi++)
#pragma unroll
    for (int r = 0; r < 4; r++) {
      float l = lsum[mi][r];
      l += __shfl_xor(l, 1, 64);
      l += __shfl_xor(l, 2, 64);
      l += __shfl_xor(l, 4, 64);
      l += __shfl_xor(l, 8, 64);
      if (l15 == 0) Lpart[pb + mi*16 + q*4 + r] = l;
    }
#pragma unroll
  for (int mi = 0; mi < 2; mi++)
#pragma unroll
    for (int dc = 0; dc < 8; dc++)
#pragma unroll
      for (int r = 0; r < 4; r++)
        Opart[(pb + mi*16 + q*4 + r) * 128 + dc*16 + l15] = oacc[mi][dc][r];
}

// ---------- combine partials -> Ao bf16 [m][2048] ----------
__global__ __launch_bounds__(256) void attn_combine_kernel(
    const float* __restrict__ Opart, const float* __restrict__ Lpart,
    unsigned short* __restrict__ Ao)
{
  const size_t TS = 4194304ull;   // tpar stride in floats (32*1024*128)
  int gid = blockIdx.x * 256 + threadIdx.x;
  int idx = gid * 8;              // over 2048*2048
  int m = idx >> 11, n0 = idx & 2047;
  int b = m >> 10, s = m & 1023;
  int h, d2_0;
  if (n0 < 1024) { h = n0 >> 6; d2_0 = n0 & 63; }
  else { h = (n0 - 1024) >> 6; d2_0 = 64 + ((n0 - 1024) & 63); }
  int bh = b*16 + h;
  size_t ob = ((size_t)bh * 1024 + s) * 128 + d2_0;
  float l0 = Lpart[(size_t)bh * 1024 + s];
  float l1 = Lpart[TS/128 + (size_t)bh * 1024 + s];   // Lpart tpar stride = 32*1024
  float inv = 1.f / (l0 + l1);
  float4 x0 = *(const float4*)&Opart[ob];
  float4 x1 = *(const float4*)&Opart[ob + 4];
  float4 y0 = *(const float4*)&Opart[ob + TS];
  float4 y1 = *(const float4*)&Opart[ob + TS + 4];
  US8 o;
  o.u[0] = f2bf((x0.x + y0.x) * inv); o.u[1] = f2bf((x0.y + y0.y) * inv);
  o.u[2] = f2bf((x0.z + y0.z) * inv); o.u[3] = f2bf((x0.w + y0.w) * inv);
  o.u[4] = f2bf((x1.x + y1.x) * inv); o.u[5] = f2bf((x1.y + y1.y) * inv);
  o.u[6] = f2bf((x1.z + y1.z) * inv); o.u[7] = f2bf((x1.w + y1.w) * inv);
  *(US8*)&Ao[idx] = o;
}

// ---------- launch ----------
extern "C" void kernel_launch(void* const* d_in, const int* in_sizes, int n_in,
                              void* d_out, int out_size, void* d_ws, size_t ws_size,
                              hipStream_t stream)
{
  (void)in_sizes; (void)n_in; (void)out_size; (void)ws_size;
  const float* hre = (const float*)d_in[0];
  const float* him = (const float*)d_in[1];
  const float* Kcr = (const float*)d_in[2];
  const float* Kci = (const float*)d_in[3];
  const float* Vcr = (const float*)d_in[4];
  const float* Vci = (const float*)d_in[5];
  const float* gamma = (const float*)d_in[6];
  const float* bre = (const float*)d_in[7];
  const float* bim = (const float*)d_in[8];
  const float* qWr = (const float*)d_in[9];
  const float* qWi = (const float*)d_in[10];
  const float* qbr = (const float*)d_in[11];
  const float* qbi = (const float*)d_in[12];
  const float* kWr = (const float*)d_in[13];
  const float* kWi = (const float*)d_in[14];
  const float* kbr = (const float*)d_in[15];
  const float* kbi = (const float*)d_in[16];
  const float* vWr = (const float*)d_in[17];
  const float* vWi = (const float*)d_in[18];
  const float* vbr = (const float*)d_in[19];
  const float* vbi = (const float*)d_in[20];
  const float* oWr = (const float*)d_in[21];
  const float* oWi = (const float*)d_in[22];
  const float* obr = (const float*)d_in[23];
  const float* obi = (const float*)d_in[24];
  float* out = (float*)d_out;

  char* ws = (char*)d_ws;
  size_t off = 0;
  auto carve = [&](size_t bytes) {
    char* p = ws + off;
    off += (bytes + 255) & ~(size_t)255;
    return p;
  };
  unsigned short* Aln = (unsigned short*)carve(2048ull * 2048 * 2);       // 8 MB
  unsigned short* Wc  = (unsigned short*)carve(4ull * 2048 * 2048 * 2);   // 32 MB
  float*          bc  = (float*)carve(4ull * 2048 * 4);                   // 32 KB
  float*          Cqkv= (float*)carve(2048ull * 6144 * 4);                // 48 MB
  unsigned short* Qp  = (unsigned short*)carve(4194304ull * 2);           // 8 MB
  unsigned short* Kp  = (unsigned short*)carve(16777216ull * 2);          // 32 MB
  unsigned short* Vt  = (unsigned short*)carve(16777216ull * 2);          // 32 MB
  unsigned short* Ao  = (unsigned short*)carve(2048ull * 2048 * 2);       // 8 MB

  // Opart/Lpart overlay regions no longer live at attn time:
  float* Opart = (float*)Cqkv;   // 33.6 MB <= 48 MB; Cqkv last read by pack_vt (pre-attn)
  float* Lpart = (float*)Aln;    // 256 KB  <= 8 MB;  Aln last read by gemm_bt

  // output chunk offsets (floats)
  float* out_Kre = out + 4194304;
  float* out_Kim = out + 4194304 + 8388608;
  float* out_Vre = out + 4194304 + 2 * 8388608;
  float* out_Vim = out + 4194304 + 3 * 8388608;

  hipLaunchKernelGGL(ln_kernel, dim3(2048), dim3(256), 0, stream,
                     hre, him, gamma, bre, bim, Aln);
  hipLaunchKernelGGL(wprep_kernel, dim3(8192), dim3(256), 0, stream,
                     qWr, qWi, kWr, kWi, vWr, vWi, oWr, oWi, Wc);
  hipLaunchKernelGGL(bprep_kernel, dim3(32), dim3(256), 0, stream,
                     qbr, qbi, kbr, kbi, vbr, vbi, obr, obi, bc);
  hipLaunchKernelGGL(gemm_bt_kernel, dim3(48, 16), dim3(256), 0, stream,
                     Aln, Wc, bc, Cqkv, 6144, 2048);
  hipLaunchKernelGGL(pack_q_kernel, dim3(4096), dim3(256), 0, stream, Cqkv, Qp);
  hipLaunchKernelGGL(pack_kv_kernel, dim3(16384), dim3(256), 0, stream,
                     Kcr, Kci, Cqkv, 2048, Kp, out_Kre, out_Kim);
  hipLaunchKernelGGL(pack_kv_kernel, dim3(16384), dim3(256), 0, stream,
                     Vcr, Vci, Cqkv, 4096, (unsigned short*)nullptr, out_Vre, out_Vim);
  hipLaunchKernelGGL(pack_vt_kernel, dim3(2048), dim3(256), 0, stream,
                     Vcr, Vci, Cqkv, Vt);
  hipLaunchKernelGGL(attn_kernel, dim3(32, 8, 2), dim3(256), 0, stream,
                     Qp, Kp, Vt, Opart, Lpart);
  hipLaunchKernelGGL(attn_combine_kernel, dim3(2048), dim3(256), 0, stream,
                     Opart, Lpart, Ao);
  hipLaunchKernelGGL(gemm_oproj_kernel, dim3(16, 16), dim3(256), 0, stream,
                     Ao, Wc + 3ull * 2048 * 2048, bc + 3 * 2048, hre, him, out);
}